// Round 1
// baseline (2219.666 us; speedup 1.0000x reference)
//
#include <hip/hip_runtime.h>
#include <hip/hip_bf16.h>
#include <math.h>

#define N_NODES 100000
#define N_EDGES 1600000
#define NHEADS 4
#define NEG_SLOPE 0.2f
// D = H * D_hid = 128 channels for both layers

// ---------------------------------------------------------------------------
// GEMM 128x128: out[r][c] = sum_k x[r][k] * W[k][c]
// Each lane holds one column of W in 128 VGPRs; wave pair covers 128 cols.
// x row is wave-uniform -> scalar loads. Pure-FMA inner loop.
// ---------------------------------------------------------------------------
__global__ __launch_bounds__(256) void gemm128_kernel(
        const float* __restrict__ x, const float* __restrict__ W,
        float* __restrict__ out, int n_rows) {
    const int lane = threadIdx.x & 63;
    const int wave = threadIdx.x >> 6;
    const int col  = (wave & 1) * 64 + lane;

    float w[128];
#pragma unroll
    for (int k = 0; k < 128; ++k) w[k] = W[k * 128 + col];

    const int team   = blockIdx.x * 2 + (wave >> 1);
    const int nteams = gridDim.x * 2;
    for (int r = team; r < n_rows; r += nteams) {
        const float* xr = x + (size_t)__builtin_amdgcn_readfirstlane(r) * 128;
        float acc = 0.f;
#pragma unroll
        for (int k = 0; k < 128; ++k) acc = fmaf(xr[k], w[k], acc);
        out[(size_t)r * 128 + col] = acc;
    }
}

// ---------------------------------------------------------------------------
// Per-node attention logits: es[n,h] = <h[n,h,:], a_src[h,:]>, same for ed.
// One thread per (node, head).
// ---------------------------------------------------------------------------
__global__ void attn_scores_kernel(const float* __restrict__ h,
                                   const float* __restrict__ a_src,
                                   const float* __restrict__ a_dst,
                                   float* __restrict__ es,
                                   float* __restrict__ ed) {
    int idx = blockIdx.x * 256 + threadIdx.x;
    if (idx >= N_NODES * NHEADS) return;
    int n = idx >> 2, hd = idx & 3;
    const float* hr = h + (size_t)n * 128 + hd * 32;
    const float* as = a_src + hd * 32;
    const float* ad = a_dst + hd * 32;
    float s = 0.f, d = 0.f;
#pragma unroll
    for (int k = 0; k < 32; ++k) {
        float v = hr[k];
        s = fmaf(v, as[k], s);
        d = fmaf(v, ad[k], d);
    }
    es[idx] = s;
    ed[idx] = d;
}

// ---------------------------------------------------------------------------
// Edge aggregation (softmax shift dropped; it's mathematically invariant and
// logits are O(10) so exp() is safe in fp32):
//   w   = exp(leaky_relu(es[src] + ed[dst]))
//   acc[dst] += w * h[src]   (unnormalized; divide by den in finalize)
//   den[dst] += w
// 128 threads per edge (one per channel).
// ---------------------------------------------------------------------------
__global__ void edge_aggregate_kernel(const int* __restrict__ src,
                                      const int* __restrict__ dst,
                                      const float* __restrict__ es,
                                      const float* __restrict__ ed,
                                      const float* __restrict__ h,
                                      float* __restrict__ acc,
                                      float* __restrict__ den) {
    unsigned int tid = blockIdx.x * 256u + threadIdx.x;
    int e = (int)(tid >> 7);
    if (e >= N_EDGES) return;
    int c = (int)(tid & 127u);
    int hd = c >> 5;
    int s = src[e], d = dst[e];
    float sc = es[s * 4 + hd] + ed[d * 4 + hd];
    sc = sc > 0.f ? sc : NEG_SLOPE * sc;
    float w = __expf(sc);
    atomicAdd(&acc[(size_t)d * 128 + c], w * h[(size_t)s * 128 + c]);
    if ((c & 31) == 0) atomicAdd(&den[d * 4 + hd], w);
}

// ---------------------------------------------------------------------------
// Layer-1 finalize (elementwise, in place): x1 = relu(acc/den + b1)
// ---------------------------------------------------------------------------
__global__ void finalize_relu_kernel(float* __restrict__ acc,
                                     const float* __restrict__ den,
                                     const float* __restrict__ b) {
    int idx = blockIdx.x * 256 + threadIdx.x;
    if (idx >= N_NODES * 128) return;
    int c = idx & 127, n = idx >> 7, hd = c >> 5;
    float de = den[n * 4 + hd];
    float v = (de > 0.f ? acc[idx] / de : 0.f) + b[c];
    acc[idx] = v > 0.f ? v : 0.f;
}

// ---------------------------------------------------------------------------
// Layer-2 finalize + log_softmax over the 128 channels. One wave per node,
// 2 channels per lane, butterfly shuffles for max and sum.
// ---------------------------------------------------------------------------
__global__ void finalize_logsoftmax_kernel(const float* __restrict__ acc,
                                           const float* __restrict__ den,
                                           const float* __restrict__ b,
                                           float* __restrict__ out) {
    int wave = threadIdx.x >> 6, lane = threadIdx.x & 63;
    int n = blockIdx.x * 4 + wave;
    if (n >= N_NODES) return;
    int c0 = lane * 2;
    int hd = c0 >> 5;  // both channels in the same 32-wide head
    float de = den[n * 4 + hd];
    float2 a = *(const float2*)(acc + (size_t)n * 128 + c0);
    float v0 = (de > 0.f ? a.x / de : 0.f) + b[c0];
    float v1 = (de > 0.f ? a.y / de : 0.f) + b[c0 + 1];

    float m = fmaxf(v0, v1);
#pragma unroll
    for (int s = 1; s < 64; s <<= 1) m = fmaxf(m, __shfl_xor(m, s));
    float sum = __expf(v0 - m) + __expf(v1 - m);
#pragma unroll
    for (int s = 1; s < 64; s <<= 1) sum += __shfl_xor(sum, s);
    float ls = m + logf(sum);

    float* o = out + (size_t)n * 128 + c0;
    o[0] = v0 - ls;
    o[1] = v1 - ls;
}

// ---------------------------------------------------------------------------
extern "C" void kernel_launch(void* const* d_in, const int* in_sizes, int n_in,
                              void* d_out, int out_size, void* d_ws, size_t ws_size,
                              hipStream_t stream) {
    const int*   edge = (const int*)d_in[0];     // (2, E)
    const int*   src  = edge;
    const int*   dst  = edge + N_EDGES;
    const float* feat = (const float*)d_in[1];   // (N, 128)
    const float* W1   = (const float*)d_in[2];
    const float* a1s  = (const float*)d_in[3];
    const float* a1d  = (const float*)d_in[4];
    const float* b1   = (const float*)d_in[5];
    const float* W2   = (const float*)d_in[6];
    const float* a2s  = (const float*)d_in[7];
    const float* a2d  = (const float*)d_in[8];
    const float* b2   = (const float*)d_in[9];
    float* out = (float*)d_out;

    // Workspace layout (fp32): h (N*128) | acc (N*128) | es (N*4) | ed (N*4) | den (N*4)
    float* ws  = (float*)d_ws;
    float* h   = ws;
    float* acc = ws + (size_t)N_NODES * 128;
    float* es  = ws + (size_t)N_NODES * 256;
    float* ed  = es + (size_t)N_NODES * 4;
    float* den = ed + (size_t)N_NODES * 4;

    const int edge_blocks = (N_EDGES * 128) / 256;          // 800000
    const int node_blocks = (N_NODES * 128) / 256;          // 50000
    const int score_blocks = (N_NODES * NHEADS + 255) / 256;

    // ---- Layer 1 ----
    hipMemsetAsync(acc, 0, (size_t)N_NODES * 128 * sizeof(float), stream);
    hipMemsetAsync(den, 0, (size_t)N_NODES * 4 * sizeof(float), stream);
    gemm128_kernel<<<1024, 256, 0, stream>>>(feat, W1, h, N_NODES);
    attn_scores_kernel<<<score_blocks, 256, 0, stream>>>(h, a1s, a1d, es, ed);
    edge_aggregate_kernel<<<edge_blocks, 256, 0, stream>>>(src, dst, es, ed, h, acc, den);
    finalize_relu_kernel<<<node_blocks, 256, 0, stream>>>(acc, den, b1);  // acc -> x1

    // ---- Layer 2 ----
    gemm128_kernel<<<1024, 256, 0, stream>>>(acc, W2, h, N_NODES);        // h = h2
    // acc (x1) is dead after gemm2; reuse it as acc2
    hipMemsetAsync(acc, 0, (size_t)N_NODES * 128 * sizeof(float), stream);
    hipMemsetAsync(den, 0, (size_t)N_NODES * 4 * sizeof(float), stream);
    attn_scores_kernel<<<score_blocks, 256, 0, stream>>>(h, a2s, a2d, es, ed);
    edge_aggregate_kernel<<<edge_blocks, 256, 0, stream>>>(src, dst, es, ed, h, acc, den);
    finalize_logsoftmax_kernel<<<(N_NODES + 3) / 4, 256, 0, stream>>>(acc, den, b2, out);
}

// Round 2
// 968.394 us; speedup vs baseline: 2.2921x; 2.2921x over previous
//
#include <hip/hip_runtime.h>
#include <hip/hip_bf16.h>
#include <math.h>

#define N_NODES 100000
#define N_EDGES 1600000
#define NHEADS 4
#define NEG_SLOPE 0.2f
// D = H * D_hid = 128 channels for both layers

// ---------------------------------------------------------------------------
// GEMM 128x128: out[r][c] = sum_k x[r][k] * W[k][c]
// Each lane holds one column of W in 128 VGPRs; wave pair covers 128 cols.
// x row is wave-uniform -> scalar loads. Pure-FMA inner loop.
// ---------------------------------------------------------------------------
__global__ __launch_bounds__(256) void gemm128_kernel(
        const float* __restrict__ x, const float* __restrict__ W,
        float* __restrict__ out, int n_rows) {
    const int lane = threadIdx.x & 63;
    const int wave = threadIdx.x >> 6;
    const int col  = (wave & 1) * 64 + lane;

    float w[128];
#pragma unroll
    for (int k = 0; k < 128; ++k) w[k] = W[k * 128 + col];

    const int team   = blockIdx.x * 2 + (wave >> 1);
    const int nteams = gridDim.x * 2;
    for (int r = team; r < n_rows; r += nteams) {
        const float* xr = x + (size_t)__builtin_amdgcn_readfirstlane(r) * 128;
        float acc = 0.f;
#pragma unroll
        for (int k = 0; k < 128; ++k) acc = fmaf(xr[k], w[k], acc);
        out[(size_t)r * 128 + col] = acc;
    }
}

// ---------------------------------------------------------------------------
// Per-node attention logits: es[n,h] = <h[n,h,:], a_src[h,:]>, same for ed.
// One thread per (node, head).
// ---------------------------------------------------------------------------
__global__ void attn_scores_kernel(const float* __restrict__ h,
                                   const float* __restrict__ a_src,
                                   const float* __restrict__ a_dst,
                                   float* __restrict__ es,
                                   float* __restrict__ ed) {
    int idx = blockIdx.x * 256 + threadIdx.x;
    if (idx >= N_NODES * NHEADS) return;
    int n = idx >> 2, hd = idx & 3;
    const float* hr = h + (size_t)n * 128 + hd * 32;
    const float* as = a_src + hd * 32;
    const float* ad = a_dst + hd * 32;
    float s = 0.f, d = 0.f;
#pragma unroll
    for (int k = 0; k < 32; ++k) {
        float v = hr[k];
        s = fmaf(v, as[k], s);
        d = fmaf(v, ad[k], d);
    }
    es[idx] = s;
    ed[idx] = d;
}

// ---------------------------------------------------------------------------
// CSR build (graph is the same for both layers -> build once, use twice).
// ---------------------------------------------------------------------------
__global__ void zero_ints_kernel(int* __restrict__ p, int n) {
    int i = blockIdx.x * 256 + threadIdx.x;
    if (i < n) p[i] = 0;
}

__global__ void csr_histogram_kernel(const int* __restrict__ dst,
                                     int* __restrict__ deg) {
    int e = blockIdx.x * 256 + threadIdx.x;
    if (e < N_EDGES) atomicAdd(&deg[dst[e]], 1);
}

// Exclusive scan, step 1: per-block scan + block sums.
__global__ __launch_bounds__(256) void scan1_kernel(const int* __restrict__ deg,
                                                    int* __restrict__ rowptr,
                                                    int* __restrict__ partials) {
    __shared__ int wsum[4];
    int i = blockIdx.x * 256 + threadIdx.x;
    int lane = threadIdx.x & 63, wave = threadIdx.x >> 6;
    int orig = (i < N_NODES) ? deg[i] : 0;
    int v = orig;
#pragma unroll
    for (int off = 1; off < 64; off <<= 1) {
        int t = __shfl_up(v, off);
        if (lane >= off) v += t;
    }
    if (lane == 63) wsum[wave] = v;
    __syncthreads();
    int woff = 0;
#pragma unroll
    for (int w = 0; w < 4; ++w) if (w < wave) woff += wsum[w];
    if (i < N_NODES) rowptr[i] = v - orig + woff;
    if (threadIdx.x == 0)
        partials[blockIdx.x] = wsum[0] + wsum[1] + wsum[2] + wsum[3];
}

// Exclusive scan, step 2: scan the (<=512) block sums with a single block.
__global__ __launch_bounds__(512) void scan2_kernel(int* __restrict__ partials,
                                                    int nb) {
    __shared__ int wsum[8];
    int i = threadIdx.x;
    int lane = i & 63, wave = i >> 6;
    int orig = (i < nb) ? partials[i] : 0;
    int v = orig;
#pragma unroll
    for (int off = 1; off < 64; off <<= 1) {
        int t = __shfl_up(v, off);
        if (lane >= off) v += t;
    }
    if (lane == 63) wsum[wave] = v;
    __syncthreads();
    int woff = 0;
#pragma unroll
    for (int w = 0; w < 8; ++w) if (w < wave) woff += wsum[w];
    if (i < nb) partials[i] = v - orig + woff;
}

__global__ void scan3_kernel(int* __restrict__ rowptr,
                             const int* __restrict__ partials) {
    int i = blockIdx.x * 256 + threadIdx.x;
    if (i < N_NODES) rowptr[i] += partials[blockIdx.x];
}

__global__ void csr_fill_kernel(const int* __restrict__ src,
                                const int* __restrict__ dst,
                                const int* __restrict__ rowptr,
                                int* __restrict__ fillc,
                                int* __restrict__ csr_src) {
    int e = blockIdx.x * 256 + threadIdx.x;
    if (e >= N_EDGES) return;
    int d = dst[e];
    int pos = rowptr[d] + atomicAdd(&fillc[d], 1);
    csr_src[pos] = src[e];
}

// ---------------------------------------------------------------------------
// Gather aggregation, one wave per dst node, 2 channels per lane.
//   acc += w * h[src], wsum += w  (registers only, zero atomics)
// Epilogue fused: RELU path (layer 1) or log_softmax path (layer 2).
// Softmax max-shift dropped: shift-invariant, logits are O(1) in fp32.
// ---------------------------------------------------------------------------
template <bool LOGSOFTMAX>
__global__ __launch_bounds__(256) void aggregate_kernel(
        const int* __restrict__ csr_src, const int* __restrict__ rowptr,
        const int* __restrict__ deg,
        const float* __restrict__ es, const float* __restrict__ ed,
        const float* __restrict__ h, const float* __restrict__ b,
        float* __restrict__ out) {
    const int lane = threadIdx.x & 63;
    const int wave = threadIdx.x >> 6;
    const int n = blockIdx.x * 4 + wave;
    if (n >= N_NODES) return;
    const int c0 = lane * 2;
    const int hd = c0 >> 5;           // both channels in the same head
    const float edn = ed[n * 4 + hd];
    const int base = rowptr[n];
    const int dg = deg[n];

    float a0 = 0.f, a1 = 0.f, wsum = 0.f;
    for (int j = 0; j < dg; ++j) {
        int s = csr_src[base + j];    // wave-uniform -> broadcast load
        float sc = es[s * 4 + hd] + edn;
        sc = sc > 0.f ? sc : NEG_SLOPE * sc;
        float w = __expf(sc);
        float2 hv = *(const float2*)(h + (size_t)s * 128 + c0);
        a0 = fmaf(w, hv.x, a0);
        a1 = fmaf(w, hv.y, a1);
        wsum += w;
    }
    float inv = wsum > 0.f ? 1.f / wsum : 0.f;
    float v0 = a0 * inv + b[c0];
    float v1 = a1 * inv + b[c0 + 1];

    float* o = out + (size_t)n * 128 + c0;
    if (!LOGSOFTMAX) {
        o[0] = v0 > 0.f ? v0 : 0.f;
        o[1] = v1 > 0.f ? v1 : 0.f;
    } else {
        float m = fmaxf(v0, v1);
#pragma unroll
        for (int s = 1; s < 64; s <<= 1) m = fmaxf(m, __shfl_xor(m, s));
        float sum = __expf(v0 - m) + __expf(v1 - m);
#pragma unroll
        for (int s = 1; s < 64; s <<= 1) sum += __shfl_xor(sum, s);
        float ls = m + logf(sum);
        o[0] = v0 - ls;
        o[1] = v1 - ls;
    }
}

// ---------------------------------------------------------------------------
extern "C" void kernel_launch(void* const* d_in, const int* in_sizes, int n_in,
                              void* d_out, int out_size, void* d_ws, size_t ws_size,
                              hipStream_t stream) {
    const int*   edge = (const int*)d_in[0];     // (2, E)
    const int*   src  = edge;
    const int*   dst  = edge + N_EDGES;
    const float* feat = (const float*)d_in[1];   // (N, 128)
    const float* W1   = (const float*)d_in[2];
    const float* a1s  = (const float*)d_in[3];
    const float* a1d  = (const float*)d_in[4];
    const float* b1   = (const float*)d_in[5];
    const float* W2   = (const float*)d_in[6];
    const float* a2s  = (const float*)d_in[7];
    const float* a2d  = (const float*)d_in[8];
    const float* b2   = (const float*)d_in[9];
    float* out = (float*)d_out;

    // Workspace layout: h (N*128 f32) | x1 (N*128 f32) | es,ed (N*4 f32 each)
    //                 | deg | rowptr | fillc (N int each) | partials (512 int)
    //                 | csr_src (E int)
    float* ws  = (float*)d_ws;
    float* h   = ws;
    float* x1  = ws + (size_t)N_NODES * 128;
    float* es  = ws + (size_t)N_NODES * 256;
    float* ed  = es + (size_t)N_NODES * 4;
    int*   deg     = (int*)(ed + (size_t)N_NODES * 4);
    int*   rowptr  = deg + N_NODES;
    int*   fillc   = rowptr + N_NODES;
    int*   partials = fillc + N_NODES;
    int*   csr_src = partials + 512;

    const int node_blk  = (N_NODES + 255) / 256;     // 391
    const int edge_blk  = (N_EDGES + 255) / 256;     // 6250
    const int score_blk = (N_NODES * NHEADS + 255) / 256;
    const int agg_blk   = (N_NODES + 3) / 4;         // 25000

    // ---- CSR build (shared by both layers) ----
    zero_ints_kernel<<<node_blk, 256, 0, stream>>>(deg, N_NODES);
    zero_ints_kernel<<<node_blk, 256, 0, stream>>>(fillc, N_NODES);
    csr_histogram_kernel<<<edge_blk, 256, 0, stream>>>(dst, deg);
    scan1_kernel<<<node_blk, 256, 0, stream>>>(deg, rowptr, partials);
    scan2_kernel<<<1, 512, 0, stream>>>(partials, node_blk);
    scan3_kernel<<<node_blk, 256, 0, stream>>>(rowptr, partials);
    csr_fill_kernel<<<edge_blk, 256, 0, stream>>>(src, dst, rowptr, fillc, csr_src);

    // ---- Layer 1 ----
    gemm128_kernel<<<1024, 256, 0, stream>>>(feat, W1, h, N_NODES);
    attn_scores_kernel<<<score_blk, 256, 0, stream>>>(h, a1s, a1d, es, ed);
    aggregate_kernel<false><<<agg_blk, 256, 0, stream>>>(
        csr_src, rowptr, deg, es, ed, h, b1, x1);

    // ---- Layer 2 ----
    gemm128_kernel<<<1024, 256, 0, stream>>>(x1, W2, h, N_NODES);
    attn_scores_kernel<<<score_blk, 256, 0, stream>>>(h, a2s, a2d, es, ed);
    aggregate_kernel<true><<<agg_blk, 256, 0, stream>>>(
        csr_src, rowptr, deg, es, ed, h, b2, out);
}

// Round 3
// 675.437 us; speedup vs baseline: 3.2863x; 1.4337x over previous
//
#include <hip/hip_runtime.h>
#include <hip/hip_bf16.h>
#include <math.h>

#define N_NODES 100000
#define N_EDGES 1600000
#define NHEADS 4
#define NEG_SLOPE 0.2f
// D = H * D_hid = 128 channels for both layers

// ---------------------------------------------------------------------------
// Fused GEMM (out = x @ W, 128x128) + attention scores (es/ed dots).
// Block: 256 threads -> tile of 64 rows x 128 cols. Thread: 4 rows x 8 cols.
// W staged in LDS in two K-halves, col-blocked [16 cblk][64 k][8 f] with
// stride 516 (pad +4): read bank = (4*tn + 8k) % 32 -> 2-way alias = free.
// 33 KB LDS -> 3 blocks/CU with __launch_bounds__(256,3).
// x rows stream through registers (float4 per 4-k chunk, double-buffered);
// the 16 lanes of a col-row-group read the same address -> HW broadcast.
// Epilogue: write h tile + per-head dot with a_src/a_dst reduced via
// shfl_xor over the 4 col-groups per head -> es/ed (replaces attn kernel).
// ---------------------------------------------------------------------------
__global__ __launch_bounds__(256, 3) void gemm_fused_kernel(
        const float* __restrict__ x, const float* __restrict__ W,
        const float* __restrict__ a_src, const float* __restrict__ a_dst,
        float* __restrict__ h, float* __restrict__ es, float* __restrict__ ed,
        int n_rows) {
    __shared__ float Wl[16 * 516];  // 33024 B

    const int t  = threadIdx.x;
    const int tn = t & 15;                 // col group: cols tn*8..tn*8+7
    const int tm = t >> 4;                 // row group: rows tm*4..tm*4+3
    const int c0 = tn * 8;
    const int rbase = blockIdx.x * 64 + tm * 4;

    float acc[4][8];
#pragma unroll
    for (int i = 0; i < 4; ++i)
#pragma unroll
        for (int j = 0; j < 8; ++j) acc[i][j] = 0.f;

    bool rv[4];
    const float* xrow[4];
#pragma unroll
    for (int i = 0; i < 4; ++i) {
        int r = rbase + i;
        rv[i] = r < n_rows;
        xrow[i] = x + (size_t)(rv[i] ? r : 0) * 128;
    }

    for (int half = 0; half < 2; ++half) {
        const int k0 = half * 64;
        if (half) __syncthreads();         // finish reads of previous half
        // stage 64 k-rows of W: 8192 floats = 2048 float4, 8 per thread
#pragma unroll
        for (int p = 0; p < 8; ++p) {
            int idx = (p * 256 + t) * 4;   // float index 0..8191
            int kk = idx >> 7;             // 0..63
            int c  = idx & 127;
            float4 v = *(const float4*)(W + (size_t)(k0 + kk) * 128 + c);
            *(float4*)&Wl[(c >> 3) * 516 + kk * 8 + (c & 7)] = v;
        }
        __syncthreads();

        float4 xcur[4], xnxt[4];
#pragma unroll
        for (int i = 0; i < 4; ++i) {
            xcur[i] = rv[i] ? *(const float4*)(xrow[i] + k0)
                            : make_float4(0.f, 0.f, 0.f, 0.f);
            xnxt[i] = xcur[i];
        }
        for (int kb = 0; kb < 16; ++kb) {
            if (kb < 15) {
#pragma unroll
                for (int i = 0; i < 4; ++i)
                    xnxt[i] = rv[i] ? *(const float4*)(xrow[i] + k0 + (kb + 1) * 4)
                                    : make_float4(0.f, 0.f, 0.f, 0.f);
            }
#pragma unroll
            for (int kk = 0; kk < 4; ++kk) {
                const int ks = kb * 4 + kk;
                const float* wp = &Wl[tn * 516 + ks * 8];
                float4 w0 = *(const float4*)wp;
                float4 w1 = *(const float4*)(wp + 4);
#pragma unroll
                for (int i = 0; i < 4; ++i) {
                    const float* xf = (const float*)&xcur[i];
                    float xs = xf[kk];
                    acc[i][0] = fmaf(xs, w0.x, acc[i][0]);
                    acc[i][1] = fmaf(xs, w0.y, acc[i][1]);
                    acc[i][2] = fmaf(xs, w0.z, acc[i][2]);
                    acc[i][3] = fmaf(xs, w0.w, acc[i][3]);
                    acc[i][4] = fmaf(xs, w1.x, acc[i][4]);
                    acc[i][5] = fmaf(xs, w1.y, acc[i][5]);
                    acc[i][6] = fmaf(xs, w1.z, acc[i][6]);
                    acc[i][7] = fmaf(xs, w1.w, acc[i][7]);
                }
            }
#pragma unroll
            for (int i = 0; i < 4; ++i) xcur[i] = xnxt[i];
        }
    }

    // ---- epilogue: write h tile + fused attention scores ----
    const int hd = tn >> 2;                 // head of this col group
    float as8[8], ad8[8];
    *(float4*)&as8[0] = *(const float4*)(a_src + c0);
    *(float4*)&as8[4] = *(const float4*)(a_src + c0 + 4);
    *(float4*)&ad8[0] = *(const float4*)(a_dst + c0);
    *(float4*)&ad8[4] = *(const float4*)(a_dst + c0 + 4);

#pragma unroll
    for (int i = 0; i < 4; ++i) {
        float ps = 0.f, pd = 0.f;
#pragma unroll
        for (int j = 0; j < 8; ++j) {
            ps = fmaf(acc[i][j], as8[j], ps);
            pd = fmaf(acc[i][j], ad8[j], pd);
        }
        // reduce over the 4 col-groups of this head (lanes differ in bits 0-1;
        // partners share tm, so the row-valid mask is uniform across them)
        ps += __shfl_xor(ps, 1); ps += __shfl_xor(ps, 2);
        pd += __shfl_xor(pd, 1); pd += __shfl_xor(pd, 2);
        if (rv[i]) {
            int r = rbase + i;
            float* hp = h + (size_t)r * 128 + c0;
            *(float4*)hp = make_float4(acc[i][0], acc[i][1], acc[i][2], acc[i][3]);
            *(float4*)(hp + 4) = make_float4(acc[i][4], acc[i][5], acc[i][6], acc[i][7]);
            if ((tn & 3) == 0) {
                es[r * 4 + hd] = ps;
                ed[r * 4 + hd] = pd;
            }
        }
    }
}

// ---------------------------------------------------------------------------
// CSR build (graph is the same for both layers -> build once, use twice).
// ---------------------------------------------------------------------------
__global__ void zero_ints_kernel(int* __restrict__ p, int n) {
    int i = blockIdx.x * 256 + threadIdx.x;
    if (i < n) p[i] = 0;
}

__global__ void csr_histogram_kernel(const int* __restrict__ dst,
                                     int* __restrict__ deg) {
    int e = blockIdx.x * 256 + threadIdx.x;
    if (e < N_EDGES) atomicAdd(&deg[dst[e]], 1);
}

// Exclusive scan, step 1: per-block scan + block sums.
__global__ __launch_bounds__(256) void scan1_kernel(const int* __restrict__ deg,
                                                    int* __restrict__ rowptr,
                                                    int* __restrict__ partials) {
    __shared__ int wsum[4];
    int i = blockIdx.x * 256 + threadIdx.x;
    int lane = threadIdx.x & 63, wave = threadIdx.x >> 6;
    int orig = (i < N_NODES) ? deg[i] : 0;
    int v = orig;
#pragma unroll
    for (int off = 1; off < 64; off <<= 1) {
        int t = __shfl_up(v, off);
        if (lane >= off) v += t;
    }
    if (lane == 63) wsum[wave] = v;
    __syncthreads();
    int woff = 0;
#pragma unroll
    for (int w = 0; w < 4; ++w) if (w < wave) woff += wsum[w];
    if (i < N_NODES) rowptr[i] = v - orig + woff;
    if (threadIdx.x == 0)
        partials[blockIdx.x] = wsum[0] + wsum[1] + wsum[2] + wsum[3];
}

// Exclusive scan, step 2: scan the (<=512) block sums with a single block.
__global__ __launch_bounds__(512) void scan2_kernel(int* __restrict__ partials,
                                                    int nb) {
    __shared__ int wsum[8];
    int i = threadIdx.x;
    int lane = i & 63, wave = i >> 6;
    int orig = (i < nb) ? partials[i] : 0;
    int v = orig;
#pragma unroll
    for (int off = 1; off < 64; off <<= 1) {
        int t = __shfl_up(v, off);
        if (lane >= off) v += t;
    }
    if (lane == 63) wsum[wave] = v;
    __syncthreads();
    int woff = 0;
#pragma unroll
    for (int w = 0; w < 8; ++w) if (w < wave) woff += wsum[w];
    if (i < nb) partials[i] = v - orig + woff;
}

__global__ void scan3_kernel(int* __restrict__ rowptr,
                             const int* __restrict__ partials) {
    int i = blockIdx.x * 256 + threadIdx.x;
    if (i < N_NODES) rowptr[i] += partials[blockIdx.x];
}

__global__ void csr_fill_kernel(const int* __restrict__ src,
                                const int* __restrict__ dst,
                                const int* __restrict__ rowptr,
                                int* __restrict__ fillc,
                                int* __restrict__ csr_src) {
    int e = blockIdx.x * 256 + threadIdx.x;
    if (e >= N_EDGES) return;
    int d = dst[e];
    int pos = rowptr[d] + atomicAdd(&fillc[d], 1);
    csr_src[pos] = src[e];
}

// ---------------------------------------------------------------------------
// Gather aggregation, one wave per dst node, 2 channels per lane.
//   acc += w * h[src], wsum += w  (registers only, zero atomics)
// Software-pipelined: next edge's index/score/payload issued before the
// current edge's FMAs, overlapping one gather latency.
// Epilogue fused: RELU path (layer 1) or log_softmax path (layer 2).
// Softmax max-shift dropped: shift-invariant, logits are O(1) in fp32.
// ---------------------------------------------------------------------------
template <bool LOGSOFTMAX>
__global__ __launch_bounds__(256) void aggregate_kernel(
        const int* __restrict__ csr_src, const int* __restrict__ rowptr,
        const int* __restrict__ deg,
        const float* __restrict__ es, const float* __restrict__ ed,
        const float* __restrict__ h, const float* __restrict__ b,
        float* __restrict__ out) {
    const int lane = threadIdx.x & 63;
    const int wave = threadIdx.x >> 6;
    const int n = blockIdx.x * 4 + wave;
    if (n >= N_NODES) return;
    const int c0 = lane * 2;
    const int hd = c0 >> 5;           // both channels in the same head
    const float edn = ed[n * 4 + hd];
    const int base = rowptr[n];
    const int dg = deg[n];

    float a0 = 0.f, a1 = 0.f, wsum = 0.f;
    if (dg > 0) {
        int s = csr_src[base];
        float e = es[s * 4 + hd];
        float2 hv = *(const float2*)(h + (size_t)s * 128 + c0);
        for (int j = 0; j < dg; ++j) {
            int s2 = (j + 1 < dg) ? csr_src[base + j + 1] : s;
            float e2 = es[s2 * 4 + hd];
            float2 hv2 = *(const float2*)(h + (size_t)s2 * 128 + c0);
            float sc = e + edn;
            sc = sc > 0.f ? sc : NEG_SLOPE * sc;
            float w = __expf(sc);
            a0 = fmaf(w, hv.x, a0);
            a1 = fmaf(w, hv.y, a1);
            wsum += w;
            e = e2; hv = hv2;
        }
    }
    float inv = wsum > 0.f ? 1.f / wsum : 0.f;
    float v0 = a0 * inv + b[c0];
    float v1 = a1 * inv + b[c0 + 1];

    float* o = out + (size_t)n * 128 + c0;
    if (!LOGSOFTMAX) {
        o[0] = v0 > 0.f ? v0 : 0.f;
        o[1] = v1 > 0.f ? v1 : 0.f;
    } else {
        float m = fmaxf(v0, v1);
#pragma unroll
        for (int s = 1; s < 64; s <<= 1) m = fmaxf(m, __shfl_xor(m, s));
        float sum = __expf(v0 - m) + __expf(v1 - m);
#pragma unroll
        for (int s = 1; s < 64; s <<= 1) sum += __shfl_xor(sum, s);
        float ls = m + logf(sum);
        o[0] = v0 - ls;
        o[1] = v1 - ls;
    }
}

// ---------------------------------------------------------------------------
extern "C" void kernel_launch(void* const* d_in, const int* in_sizes, int n_in,
                              void* d_out, int out_size, void* d_ws, size_t ws_size,
                              hipStream_t stream) {
    const int*   edge = (const int*)d_in[0];     // (2, E)
    const int*   src  = edge;
    const int*   dst  = edge + N_EDGES;
    const float* feat = (const float*)d_in[1];   // (N, 128)
    const float* W1   = (const float*)d_in[2];
    const float* a1s  = (const float*)d_in[3];
    const float* a1d  = (const float*)d_in[4];
    const float* b1   = (const float*)d_in[5];
    const float* W2   = (const float*)d_in[6];
    const float* a2s  = (const float*)d_in[7];
    const float* a2d  = (const float*)d_in[8];
    const float* b2   = (const float*)d_in[9];
    float* out = (float*)d_out;

    // Workspace layout: h (N*128 f32) | x1 (N*128 f32) | es,ed (N*4 f32 each)
    //                 | deg | rowptr | fillc (N int each) | partials (512 int)
    //                 | csr_src (E int)
    float* ws  = (float*)d_ws;
    float* h   = ws;
    float* x1  = ws + (size_t)N_NODES * 128;
    float* es  = ws + (size_t)N_NODES * 256;
    float* ed  = es + (size_t)N_NODES * 4;
    int*   deg     = (int*)(ed + (size_t)N_NODES * 4);
    int*   rowptr  = deg + N_NODES;
    int*   fillc   = rowptr + N_NODES;
    int*   partials = fillc + N_NODES;
    int*   csr_src = partials + 512;

    const int node_blk  = (N_NODES + 255) / 256;     // 391
    const int edge_blk  = (N_EDGES + 255) / 256;     // 6250
    const int gemm_blk  = (N_NODES + 63) / 64;       // 1563
    const int agg_blk   = (N_NODES + 3) / 4;         // 25000

    // ---- CSR build (shared by both layers) ----
    zero_ints_kernel<<<node_blk, 256, 0, stream>>>(deg, N_NODES);
    zero_ints_kernel<<<node_blk, 256, 0, stream>>>(fillc, N_NODES);
    csr_histogram_kernel<<<edge_blk, 256, 0, stream>>>(dst, deg);
    scan1_kernel<<<node_blk, 256, 0, stream>>>(deg, rowptr, partials);
    scan2_kernel<<<1, 512, 0, stream>>>(partials, node_blk);
    scan3_kernel<<<node_blk, 256, 0, stream>>>(rowptr, partials);
    csr_fill_kernel<<<edge_blk, 256, 0, stream>>>(src, dst, rowptr, fillc, csr_src);

    // ---- Layer 1 ----
    gemm_fused_kernel<<<gemm_blk, 256, 0, stream>>>(feat, W1, a1s, a1d,
                                                    h, es, ed, N_NODES);
    aggregate_kernel<false><<<agg_blk, 256, 0, stream>>>(
        csr_src, rowptr, deg, es, ed, h, b1, x1);

    // ---- Layer 2 ----
    gemm_fused_kernel<<<gemm_blk, 256, 0, stream>>>(x1, W2, a2s, a2d,
                                                    h, es, ed, N_NODES);
    aggregate_kernel<true><<<agg_blk, 256, 0, stream>>>(
        csr_src, rowptr, deg, es, ed, h, b2, out);
}

// Round 4
// 596.309 us; speedup vs baseline: 3.7223x; 1.1327x over previous
//
#include <hip/hip_runtime.h>
#include <hip/hip_bf16.h>
#include <math.h>

#define N_NODES 100000
#define N_EDGES 1600000
#define NHEADS 4
#define NEG_SLOPE 0.2f
// D = H * D_hid = 128 channels for both layers

typedef __attribute__((ext_vector_type(8))) short short8;
typedef __attribute__((ext_vector_type(4))) float f32x4;

// float -> bf16 (round-to-nearest-even), values are finite here
__device__ __forceinline__ unsigned short f2bf(float f) {
    unsigned int u = __float_as_uint(f);
    u += 0x7fffu + ((u >> 16) & 1u);
    return (unsigned short)(u >> 16);
}
__device__ __forceinline__ float bf_lo(unsigned int u) {
    return __uint_as_float(u << 16);
}
__device__ __forceinline__ float bf_hi(unsigned int u) {
    return __uint_as_float(u & 0xffff0000u);
}

// ---------------------------------------------------------------------------
// feat fp32 -> bf16 (N*128 elements, 4 per thread)
// ---------------------------------------------------------------------------
__global__ void convert_bf16_kernel(const float* __restrict__ x,
                                    unsigned short* __restrict__ xb, int n4) {
    int i = blockIdx.x * 256 + threadIdx.x;
    if (i >= n4) return;
    float4 v = ((const float4*)x)[i];
    unsigned int lo = (unsigned int)f2bf(v.x) | ((unsigned int)f2bf(v.y) << 16);
    unsigned int hi = (unsigned int)f2bf(v.z) | ((unsigned int)f2bf(v.w) << 16);
    ((uint2*)xb)[i] = make_uint2(lo, hi);
}

// ---------------------------------------------------------------------------
// Pack W (fp32, [k=128][n=128]) into per-lane MFMA B-fragment order (bf16):
// Wp[((ct*4+kc)*64 + lane)*8 + j] = W[kc*32 + (lane>>4)*8 + j][ct*16 + (lane&15)]
// so b_frag = 16B contiguous load per lane.  16384 elements.
// ---------------------------------------------------------------------------
__global__ void pack_w_kernel(const float* __restrict__ W,
                              unsigned short* __restrict__ Wp) {
    int idx = blockIdx.x * 256 + threadIdx.x;   // 0..16383
    int j    = idx & 7;
    int lane = (idx >> 3) & 63;
    int kc   = (idx >> 9) & 3;
    int ct   = (idx >> 11) & 7;
    int k = kc * 32 + (lane >> 4) * 8 + j;
    int n = ct * 16 + (lane & 15);
    Wp[idx] = f2bf(W[k * 128 + n]);
}

// ---------------------------------------------------------------------------
// MFMA GEMM: h = x @ W  (x bf16 [n_rows][128], W packed bf16, h bf16 out).
// Block 256 thr = 4 waves; 128 rows/block (32 rows/wave as 2 row-tiles of 16).
// K = 128 as 4 chunks of 32. mfma_f32_16x16x32_bf16, fp32 accumulate.
// A-frag: lane holds A[m=lane&15][k=quad*8+j] -> contiguous 16B global load.
// B-frag: from LDS-staged Wp, contiguous 16B per lane.
// D: col=lane&15, row=quad*4+i.
// ---------------------------------------------------------------------------
__global__ __launch_bounds__(256) void gemm_mfma_kernel(
        const unsigned short* __restrict__ x,
        const unsigned short* __restrict__ Wp,
        unsigned short* __restrict__ h, int n_rows) {
    __shared__ unsigned short Wl[16384];   // 32 KB

    const int t = threadIdx.x;
    {
        const uint4* s4 = (const uint4*)Wp;
        uint4* d4 = (uint4*)Wl;
#pragma unroll
        for (int p = 0; p < 8; ++p) d4[p * 256 + t] = s4[p * 256 + t];
    }
    __syncthreads();

    const int lane = t & 63, wave = t >> 6;
    const int l15 = lane & 15, quad = lane >> 4;
    const int rbase = blockIdx.x * 128 + wave * 32;

    short8 a[2][4];
#pragma unroll
    for (int rt = 0; rt < 2; ++rt) {
        int r = rbase + rt * 16 + l15;
        r = r < n_rows ? r : n_rows - 1;         // clamp; stores are guarded
        const unsigned short* xr = x + (size_t)r * 128 + quad * 8;
#pragma unroll
        for (int kc = 0; kc < 4; ++kc)
            a[rt][kc] = *(const short8*)(xr + kc * 32);
    }

    f32x4 acc[2][8];
#pragma unroll
    for (int rt = 0; rt < 2; ++rt)
#pragma unroll
        for (int ct = 0; ct < 8; ++ct)
            acc[rt][ct] = (f32x4){0.f, 0.f, 0.f, 0.f};

#pragma unroll
    for (int ct = 0; ct < 8; ++ct) {
#pragma unroll
        for (int kc = 0; kc < 4; ++kc) {
            short8 b = *(const short8*)&Wl[((ct * 4 + kc) * 64 + lane) * 8];
            acc[0][ct] = __builtin_amdgcn_mfma_f32_16x16x32_bf16(
                a[0][kc], b, acc[0][ct], 0, 0, 0);
            acc[1][ct] = __builtin_amdgcn_mfma_f32_16x16x32_bf16(
                a[1][kc], b, acc[1][ct], 0, 0, 0);
        }
    }

#pragma unroll
    for (int rt = 0; rt < 2; ++rt) {
#pragma unroll
        for (int i = 0; i < 4; ++i) {
            int r = rbase + rt * 16 + quad * 4 + i;
            if (r < n_rows) {
                unsigned short* hp = h + (size_t)r * 128 + l15;
#pragma unroll
                for (int ct = 0; ct < 8; ++ct)
                    hp[ct * 16] = f2bf(acc[rt][ct][i]);
            }
        }
    }
}

// ---------------------------------------------------------------------------
// Attention logits from bf16 h: one thread per (node, head).
// ---------------------------------------------------------------------------
__global__ void attn_scores_kernel(const unsigned short* __restrict__ hb,
                                   const float* __restrict__ a_src,
                                   const float* __restrict__ a_dst,
                                   float* __restrict__ es,
                                   float* __restrict__ ed) {
    int idx = blockIdx.x * 256 + threadIdx.x;
    if (idx >= N_NODES * NHEADS) return;
    int n = idx >> 2, hd = idx & 3;
    const uint4* hr = (const uint4*)(hb + (size_t)n * 128 + hd * 32);
    const float* as = a_src + hd * 32;
    const float* ad = a_dst + hd * 32;
    float s = 0.f, d = 0.f;
#pragma unroll
    for (int q = 0; q < 4; ++q) {
        uint4 u = hr[q];
        int k = q * 8;
        float f;
        f = bf_lo(u.x); s = fmaf(f, as[k + 0], s); d = fmaf(f, ad[k + 0], d);
        f = bf_hi(u.x); s = fmaf(f, as[k + 1], s); d = fmaf(f, ad[k + 1], d);
        f = bf_lo(u.y); s = fmaf(f, as[k + 2], s); d = fmaf(f, ad[k + 2], d);
        f = bf_hi(u.y); s = fmaf(f, as[k + 3], s); d = fmaf(f, ad[k + 3], d);
        f = bf_lo(u.z); s = fmaf(f, as[k + 4], s); d = fmaf(f, ad[k + 4], d);
        f = bf_hi(u.z); s = fmaf(f, as[k + 5], s); d = fmaf(f, ad[k + 5], d);
        f = bf_lo(u.w); s = fmaf(f, as[k + 6], s); d = fmaf(f, ad[k + 6], d);
        f = bf_hi(u.w); s = fmaf(f, as[k + 7], s); d = fmaf(f, ad[k + 7], d);
    }
    es[idx] = s;
    ed[idx] = d;
}

// ---------------------------------------------------------------------------
// CSR build (graph is the same for both layers -> build once, use twice).
// ---------------------------------------------------------------------------
__global__ void zero_ints_kernel(int* __restrict__ p, int n) {
    int i = blockIdx.x * 256 + threadIdx.x;
    if (i < n) p[i] = 0;
}

__global__ void csr_histogram_kernel(const int* __restrict__ dst,
                                     int* __restrict__ deg) {
    int e = blockIdx.x * 256 + threadIdx.x;
    if (e < N_EDGES) atomicAdd(&deg[dst[e]], 1);
}

__global__ __launch_bounds__(256) void scan1_kernel(const int* __restrict__ deg,
                                                    int* __restrict__ rowptr,
                                                    int* __restrict__ partials) {
    __shared__ int wsum[4];
    int i = blockIdx.x * 256 + threadIdx.x;
    int lane = threadIdx.x & 63, wave = threadIdx.x >> 6;
    int orig = (i < N_NODES) ? deg[i] : 0;
    int v = orig;
#pragma unroll
    for (int off = 1; off < 64; off <<= 1) {
        int t = __shfl_up(v, off);
        if (lane >= off) v += t;
    }
    if (lane == 63) wsum[wave] = v;
    __syncthreads();
    int woff = 0;
#pragma unroll
    for (int w = 0; w < 4; ++w) if (w < wave) woff += wsum[w];
    if (i < N_NODES) rowptr[i] = v - orig + woff;
    if (threadIdx.x == 0)
        partials[blockIdx.x] = wsum[0] + wsum[1] + wsum[2] + wsum[3];
}

__global__ __launch_bounds__(512) void scan2_kernel(int* __restrict__ partials,
                                                    int nb) {
    __shared__ int wsum[8];
    int i = threadIdx.x;
    int lane = i & 63, wave = i >> 6;
    int orig = (i < nb) ? partials[i] : 0;
    int v = orig;
#pragma unroll
    for (int off = 1; off < 64; off <<= 1) {
        int t = __shfl_up(v, off);
        if (lane >= off) v += t;
    }
    if (lane == 63) wsum[wave] = v;
    __syncthreads();
    int woff = 0;
#pragma unroll
    for (int w = 0; w < 8; ++w) if (w < wave) woff += wsum[w];
    if (i < nb) partials[i] = v - orig + woff;
}

__global__ void scan3_kernel(int* __restrict__ rowptr,
                             const int* __restrict__ partials) {
    int i = blockIdx.x * 256 + threadIdx.x;
    if (i < N_NODES) rowptr[i] += partials[blockIdx.x];
}

__global__ void csr_fill_kernel(const int* __restrict__ src,
                                const int* __restrict__ dst,
                                const int* __restrict__ rowptr,
                                int* __restrict__ fillc,
                                int* __restrict__ csr_src) {
    int e = blockIdx.x * 256 + threadIdx.x;
    if (e >= N_EDGES) return;
    int d = dst[e];
    int pos = rowptr[d] + atomicAdd(&fillc[d], 1);
    csr_src[pos] = src[e];
}

// ---------------------------------------------------------------------------
// Gather aggregation over bf16 h, one wave per dst node, 2 channels/lane
// (one uint = bf16 pair per lane per edge). Register accumulate, no atomics.
// RELU epilogue writes bf16 (feeds gemm2); LOGSOFTMAX writes fp32 d_out.
// Softmax max-shift dropped: shift-invariant, logits are O(1) in fp32.
// ---------------------------------------------------------------------------
template <bool LOGSOFTMAX>
__global__ __launch_bounds__(256) void aggregate_kernel(
        const int* __restrict__ csr_src, const int* __restrict__ rowptr,
        const int* __restrict__ deg,
        const float* __restrict__ es, const float* __restrict__ ed,
        const unsigned short* __restrict__ hb, const float* __restrict__ b,
        void* __restrict__ out) {
    const int lane = threadIdx.x & 63;
    const int wave = threadIdx.x >> 6;
    const int n = blockIdx.x * 4 + wave;
    if (n >= N_NODES) return;
    const int c0 = lane * 2;
    const int hd = c0 >> 5;           // both channels in the same head
    const float edn = ed[n * 4 + hd];
    const int base = rowptr[n];
    const int dg = deg[n];

    float a0 = 0.f, a1 = 0.f, wsum = 0.f;
    if (dg > 0) {
        int s = csr_src[base];
        float e = es[s * 4 + hd];
        unsigned int u = *(const unsigned int*)(hb + (size_t)s * 128 + c0);
        for (int j = 0; j < dg; ++j) {
            int s2 = (j + 1 < dg) ? csr_src[base + j + 1] : s;
            float e2 = es[s2 * 4 + hd];
            unsigned int u2 = *(const unsigned int*)(hb + (size_t)s2 * 128 + c0);
            float sc = e + edn;
            sc = sc > 0.f ? sc : NEG_SLOPE * sc;
            float w = __expf(sc);
            a0 = fmaf(w, bf_lo(u), a0);
            a1 = fmaf(w, bf_hi(u), a1);
            wsum += w;
            e = e2; u = u2;
        }
    }
    float inv = wsum > 0.f ? 1.f / wsum : 0.f;
    float v0 = a0 * inv + b[c0];
    float v1 = a1 * inv + b[c0 + 1];

    if (!LOGSOFTMAX) {
        float r0 = v0 > 0.f ? v0 : 0.f;
        float r1 = v1 > 0.f ? v1 : 0.f;
        unsigned int pk = (unsigned int)f2bf(r0) | ((unsigned int)f2bf(r1) << 16);
        *(unsigned int*)((unsigned short*)out + (size_t)n * 128 + c0) = pk;
    } else {
        float m = fmaxf(v0, v1);
#pragma unroll
        for (int s = 1; s < 64; s <<= 1) m = fmaxf(m, __shfl_xor(m, s));
        float sum = __expf(v0 - m) + __expf(v1 - m);
#pragma unroll
        for (int s = 1; s < 64; s <<= 1) sum += __shfl_xor(sum, s);
        float ls = m + logf(sum);
        float* o = (float*)out + (size_t)n * 128 + c0;
        o[0] = v0 - ls;
        o[1] = v1 - ls;
    }
}

// ---------------------------------------------------------------------------
extern "C" void kernel_launch(void* const* d_in, const int* in_sizes, int n_in,
                              void* d_out, int out_size, void* d_ws, size_t ws_size,
                              hipStream_t stream) {
    const int*   edge = (const int*)d_in[0];     // (2, E)
    const int*   src  = edge;
    const int*   dst  = edge + N_EDGES;
    const float* feat = (const float*)d_in[1];   // (N, 128)
    const float* W1   = (const float*)d_in[2];
    const float* a1s  = (const float*)d_in[3];
    const float* a1d  = (const float*)d_in[4];
    const float* b1   = (const float*)d_in[5];
    const float* W2   = (const float*)d_in[6];
    const float* a2s  = (const float*)d_in[7];
    const float* a2d  = (const float*)d_in[8];
    const float* b2   = (const float*)d_in[9];
    float* out = (float*)d_out;

    // Workspace: hb | x1b | featb (bf16 N*128 each) | Wp1 | Wp2 (16384 bf16)
    //          | es | ed (N*4 f32) | deg | rowptr | fillc | partials | csr_src
    unsigned short* hb    = (unsigned short*)d_ws;
    unsigned short* x1b   = hb + (size_t)N_NODES * 128;
    unsigned short* featb = x1b + (size_t)N_NODES * 128;
    unsigned short* Wp1   = featb + (size_t)N_NODES * 128;
    unsigned short* Wp2   = Wp1 + 16384;
    float* es = (float*)(Wp2 + 16384);
    float* ed = es + (size_t)N_NODES * 4;
    int* deg      = (int*)(ed + (size_t)N_NODES * 4);
    int* rowptr   = deg + N_NODES;
    int* fillc    = rowptr + N_NODES;
    int* partials = fillc + N_NODES;
    int* csr_src  = partials + 512;

    const int node_blk  = (N_NODES + 255) / 256;          // 391
    const int edge_blk  = (N_EDGES + 255) / 256;          // 6250
    const int gemm_blk  = (N_NODES + 127) / 128;          // 782
    const int attn_blk  = (N_NODES * NHEADS + 255) / 256; // 1563
    const int agg_blk   = (N_NODES + 3) / 4;              // 25000
    const int cvt_blk   = (N_NODES * 128 / 4 + 255) / 256;

    // ---- CSR build (shared by both layers) ----
    zero_ints_kernel<<<node_blk, 256, 0, stream>>>(deg, N_NODES);
    zero_ints_kernel<<<node_blk, 256, 0, stream>>>(fillc, N_NODES);
    csr_histogram_kernel<<<edge_blk, 256, 0, stream>>>(dst, deg);
    scan1_kernel<<<node_blk, 256, 0, stream>>>(deg, rowptr, partials);
    scan2_kernel<<<1, 512, 0, stream>>>(partials, node_blk);
    scan3_kernel<<<node_blk, 256, 0, stream>>>(rowptr, partials);
    csr_fill_kernel<<<edge_blk, 256, 0, stream>>>(src, dst, rowptr, fillc, csr_src);

    // ---- conversions / packing ----
    convert_bf16_kernel<<<cvt_blk, 256, 0, stream>>>(feat, featb, N_NODES * 128 / 4);
    pack_w_kernel<<<64, 256, 0, stream>>>(W1, Wp1);
    pack_w_kernel<<<64, 256, 0, stream>>>(W2, Wp2);

    // ---- Layer 1 ----
    gemm_mfma_kernel<<<gemm_blk, 256, 0, stream>>>(featb, Wp1, hb, N_NODES);
    attn_scores_kernel<<<attn_blk, 256, 0, stream>>>(hb, a1s, a1d, es, ed);
    aggregate_kernel<false><<<agg_blk, 256, 0, stream>>>(
        csr_src, rowptr, deg, es, ed, hb, b1, x1b);

    // ---- Layer 2 ----
    gemm_mfma_kernel<<<gemm_blk, 256, 0, stream>>>(x1b, Wp2, hb, N_NODES);
    attn_scores_kernel<<<attn_blk, 256, 0, stream>>>(hb, a2s, a2d, es, ed);
    aggregate_kernel<true><<<agg_blk, 256, 0, stream>>>(
        csr_src, rowptr, deg, es, ed, hb, b2, out);
}

// Round 5
// 463.258 us; speedup vs baseline: 4.7914x; 1.2872x over previous
//
#include <hip/hip_runtime.h>
#include <hip/hip_bf16.h>
#include <math.h>

#define N_NODES 100000
#define N_EDGES 1600000
#define NHEADS 4
#define NEG_SLOPE 0.2f
// D = H * D_hid = 128 channels for both layers

typedef __attribute__((ext_vector_type(8))) short short8;
typedef __attribute__((ext_vector_type(4))) float f32x4;

// float -> bf16 (round-to-nearest-even), values are finite here
__device__ __forceinline__ unsigned short f2bf(float f) {
    unsigned int u = __float_as_uint(f);
    u += 0x7fffu + ((u >> 16) & 1u);
    return (unsigned short)(u >> 16);
}
__device__ __forceinline__ float bf_lo(unsigned int u) {
    return __uint_as_float(u << 16);
}
__device__ __forceinline__ float bf_hi(unsigned int u) {
    return __uint_as_float(u & 0xffff0000u);
}
__device__ __forceinline__ short8 pack8(float4 f0, float4 f1) {
    short8 v;
    v[0] = (short)f2bf(f0.x); v[1] = (short)f2bf(f0.y);
    v[2] = (short)f2bf(f0.z); v[3] = (short)f2bf(f0.w);
    v[4] = (short)f2bf(f1.x); v[5] = (short)f2bf(f1.y);
    v[6] = (short)f2bf(f1.z); v[7] = (short)f2bf(f1.w);
    return v;
}

// ---------------------------------------------------------------------------
// WA[k][c] = sum_j W[k][hd*32+j] * a[hd][j]  (c<4: a_src head c; c>=4: a_dst)
// es/ed are linear in h = x@W, so they fold into the GEMM as 8 extra columns.
// ---------------------------------------------------------------------------
__global__ void wa_kernel(const float* __restrict__ W,
                          const float* __restrict__ a_src,
                          const float* __restrict__ a_dst,
                          float* __restrict__ WA) {
    int idx = blockIdx.x * 256 + threadIdx.x;   // 0..1023
    if (idx >= 1024) return;
    int k = idx >> 3, c = idx & 7;
    int hd = c & 3;
    const float* av = (c < 4 ? a_src : a_dst) + hd * 32;
    const float* wr = W + k * 128 + hd * 32;
    float s = 0.f;
#pragma unroll
    for (int j = 0; j < 32; ++j) s = fmaf(wr[j], av[j], s);
    WA[k * 8 + c] = s;
}

// ---------------------------------------------------------------------------
// Pack [W (128x128) | WA (128x8) pad to 16] into per-lane MFMA B-fragment
// order (bf16), 9 column-tiles:
// Wp[((ct*4+kc)*64+lane)*8+j] = src[k=kc*32+(lane>>4)*8+j][n=ct*16+(lane&15)]
// ---------------------------------------------------------------------------
__global__ void pack_w_kernel(const float* __restrict__ W,
                              const float* __restrict__ WA,
                              unsigned short* __restrict__ Wp) {
    int idx = blockIdx.x * 256 + threadIdx.x;   // 0..18431
    if (idx >= 18432) return;
    int j    = idx & 7;
    int lane = (idx >> 3) & 63;
    int kc   = (idx >> 9) & 3;
    int ct   = idx >> 11;                        // 0..8
    int k = kc * 32 + ((lane >> 4) & 3) * 8 + j;
    int n = lane & 15;
    float v;
    if (ct < 8)      v = W[k * 128 + ct * 16 + n];
    else             v = (n < 8) ? WA[k * 8 + n] : 0.f;
    Wp[idx] = f2bf(v);
}

// ---------------------------------------------------------------------------
// MFMA GEMM + fused scores: [h | esd] = x @ [W | WA].
// Block 256 thr = 4 waves; 128 rows/block (2 row-tiles of 16 per wave).
// K=128 as 4 chunks, 9 col-tiles of mfma_f32_16x16x32_bf16, fp32 accumulate.
// XF32: layer-1 reads fp32 features and converts inline (no convert pass).
// D layout: col=lane&15, row=quad*4+i.
// ---------------------------------------------------------------------------
template <bool XF32>
__global__ __launch_bounds__(256) void gemm_mfma_kernel(
        const void* __restrict__ xv,
        const unsigned short* __restrict__ Wp,
        unsigned short* __restrict__ h, float* __restrict__ esd, int n_rows) {
    __shared__ unsigned short Wl[18432];   // 36 KB

    const int t = threadIdx.x;
    {
        const uint4* s4 = (const uint4*)Wp;
        uint4* d4 = (uint4*)Wl;
#pragma unroll
        for (int p = 0; p < 9; ++p) d4[p * 256 + t] = s4[p * 256 + t];
    }
    __syncthreads();

    const int lane = t & 63, wave = t >> 6;
    const int l15 = lane & 15, quad = lane >> 4;
    const int rbase = blockIdx.x * 128 + wave * 32;

    short8 a[2][4];
#pragma unroll
    for (int rt = 0; rt < 2; ++rt) {
        int r = rbase + rt * 16 + l15;
        r = r < n_rows ? r : n_rows - 1;         // clamp; stores are guarded
        if (XF32) {
            const float* xr = (const float*)xv + (size_t)r * 128 + quad * 8;
#pragma unroll
            for (int kc = 0; kc < 4; ++kc) {
                float4 f0 = *(const float4*)(xr + kc * 32);
                float4 f1 = *(const float4*)(xr + kc * 32 + 4);
                a[rt][kc] = pack8(f0, f1);
            }
        } else {
            const unsigned short* xr =
                (const unsigned short*)xv + (size_t)r * 128 + quad * 8;
#pragma unroll
            for (int kc = 0; kc < 4; ++kc)
                a[rt][kc] = *(const short8*)(xr + kc * 32);
        }
    }

    f32x4 acc[2][9];
#pragma unroll
    for (int rt = 0; rt < 2; ++rt)
#pragma unroll
        for (int ct = 0; ct < 9; ++ct)
            acc[rt][ct] = (f32x4){0.f, 0.f, 0.f, 0.f};

#pragma unroll
    for (int ct = 0; ct < 9; ++ct) {
#pragma unroll
        for (int kc = 0; kc < 4; ++kc) {
            short8 b = *(const short8*)&Wl[((ct * 4 + kc) * 64 + lane) * 8];
            acc[0][ct] = __builtin_amdgcn_mfma_f32_16x16x32_bf16(
                a[0][kc], b, acc[0][ct], 0, 0, 0);
            acc[1][ct] = __builtin_amdgcn_mfma_f32_16x16x32_bf16(
                a[1][kc], b, acc[1][ct], 0, 0, 0);
        }
    }

#pragma unroll
    for (int rt = 0; rt < 2; ++rt) {
#pragma unroll
        for (int i = 0; i < 4; ++i) {
            int r = rbase + rt * 16 + quad * 4 + i;
            if (r < n_rows) {
                unsigned short* hp = h + (size_t)r * 128 + l15;
#pragma unroll
                for (int ct = 0; ct < 8; ++ct)
                    hp[ct * 16] = f2bf(acc[rt][ct][i]);
                if (l15 < 8) esd[r * 8 + l15] = acc[rt][8][i];
            }
        }
    }
}

// ---------------------------------------------------------------------------
// CSR build (graph is the same for both layers -> build once, use twice).
// ---------------------------------------------------------------------------
__global__ void zero_ints_kernel(int* __restrict__ p, int n) {
    int i = blockIdx.x * 256 + threadIdx.x;
    if (i < n) p[i] = 0;
}

__global__ void csr_histogram_kernel(const int* __restrict__ dst,
                                     int* __restrict__ deg) {
    int e = blockIdx.x * 256 + threadIdx.x;
    if (e < N_EDGES) atomicAdd(&deg[dst[e]], 1);
}

__global__ __launch_bounds__(256) void scan1_kernel(const int* __restrict__ deg,
                                                    int* __restrict__ rowptr,
                                                    int* __restrict__ partials) {
    __shared__ int wsum[4];
    int i = blockIdx.x * 256 + threadIdx.x;
    int lane = threadIdx.x & 63, wave = threadIdx.x >> 6;
    int orig = (i < N_NODES) ? deg[i] : 0;
    int v = orig;
#pragma unroll
    for (int off = 1; off < 64; off <<= 1) {
        int t = __shfl_up(v, off);
        if (lane >= off) v += t;
    }
    if (lane == 63) wsum[wave] = v;
    __syncthreads();
    int woff = 0;
#pragma unroll
    for (int w = 0; w < 4; ++w) if (w < wave) woff += wsum[w];
    if (i < N_NODES) rowptr[i] = v - orig + woff;
    if (threadIdx.x == 0)
        partials[blockIdx.x] = wsum[0] + wsum[1] + wsum[2] + wsum[3];
}

__global__ __launch_bounds__(512) void scan2_kernel(int* __restrict__ partials,
                                                    int nb) {
    __shared__ int wsum[8];
    int i = threadIdx.x;
    int lane = i & 63, wave = i >> 6;
    int orig = (i < nb) ? partials[i] : 0;
    int v = orig;
#pragma unroll
    for (int off = 1; off < 64; off <<= 1) {
        int t = __shfl_up(v, off);
        if (lane >= off) v += t;
    }
    if (lane == 63) wsum[wave] = v;
    __syncthreads();
    int woff = 0;
#pragma unroll
    for (int w = 0; w < 8; ++w) if (w < wave) woff += wsum[w];
    if (i < nb) partials[i] = v - orig + woff;
}

__global__ void scan3_kernel(int* __restrict__ rowptr,
                             const int* __restrict__ partials) {
    int i = blockIdx.x * 256 + threadIdx.x;
    if (i < N_NODES) rowptr[i] += partials[blockIdx.x];
}

__global__ void csr_fill_kernel(const int* __restrict__ src,
                                const int* __restrict__ dst,
                                const int* __restrict__ rowptr,
                                int* __restrict__ fillc,
                                int* __restrict__ csr_src) {
    int e = blockIdx.x * 256 + threadIdx.x;
    if (e >= N_EDGES) return;
    int d = dst[e];
    int pos = rowptr[d] + atomicAdd(&fillc[d], 1);
    csr_src[pos] = src[e];
}

// ---------------------------------------------------------------------------
// Gather aggregation, one wave per dst node.
// Lane = (edge-slot eo in [0,4)) x (channel-group cl in [0,16), 8 ch each).
// 4 edges (4 full 256B rows) gathered per wave-iteration; trip ~deg/4.
// All edge indices loaded once (coalesced 64-wide) and shfl-distributed;
// payload+score prefetched 2 iterations ahead -> ~12 edges in flight.
// Cross-eo reduction: 2x shfl_xor per accumulator.
// Epilogue fused: RELU->bf16 (layer 1) or log_softmax->fp32 (layer 2).
// Softmax max-shift dropped: shift-invariant, logits are O(1) in fp32.
// ---------------------------------------------------------------------------
template <bool LOGSOFTMAX>
__global__ __launch_bounds__(256) void aggregate_kernel(
        const int* __restrict__ csr_src, const int* __restrict__ rowptr,
        const int* __restrict__ deg, const float* __restrict__ esd,
        const unsigned short* __restrict__ hb, const float* __restrict__ b,
        void* __restrict__ out) {
    const int lane = threadIdx.x & 63;
    const int wave = threadIdx.x >> 6;
    const int n = blockIdx.x * 4 + wave;
    if (n >= N_NODES) return;
    const int eo = lane >> 4;          // edge slot
    const int cl = lane & 15;          // channel group: channels cl*8..cl*8+7
    const int c0 = cl * 8;
    const int hd = cl >> 2;
    const float edn = esd[n * 8 + 4 + hd];
    const int base = rowptr[n];
    const int dg = deg[n];

    float acc[8] = {0.f, 0.f, 0.f, 0.f, 0.f, 0.f, 0.f, 0.f};
    float wsum = 0.f;

    if (dg > 0) {
        const int myidx = csr_src[base + (lane < dg ? lane : dg - 1)];
        const int nit = (dg + 3) >> 2;

        auto getS = [&](int j) -> int {
            int o = 4 * j + eo;
            if (4 * j < 64) return __shfl(myidx, o);   // j wave-uniform
            int oc = o < dg ? o : dg - 1;
            return csr_src[base + oc];
        };
        auto loadP = [&](int s) -> uint4 {
            return *(const uint4*)(hb + (size_t)s * 128 + c0);
        };

        int s0 = getS(0);
        uint4 p0 = loadP(s0);
        float e0 = esd[s0 * 8 + hd];
        uint4 p1 = p0; float e1 = e0;
        if (nit > 1) {
            int s1 = getS(1);
            p1 = loadP(s1);
            e1 = esd[s1 * 8 + hd];
        }
        for (int j = 0; j < nit; ++j) {
            uint4 p2 = p1; float e2 = e1;
            if (j + 2 < nit) {
                int s2 = getS(j + 2);
                p2 = loadP(s2);
                e2 = esd[s2 * 8 + hd];
            }
            int o = 4 * j + eo;
            float sc = e0 + edn;
            sc = sc > 0.f ? sc : NEG_SLOPE * sc;
            float w = (o < dg) ? __expf(sc) : 0.f;
            acc[0] = fmaf(w, bf_lo(p0.x), acc[0]);
            acc[1] = fmaf(w, bf_hi(p0.x), acc[1]);
            acc[2] = fmaf(w, bf_lo(p0.y), acc[2]);
            acc[3] = fmaf(w, bf_hi(p0.y), acc[3]);
            acc[4] = fmaf(w, bf_lo(p0.z), acc[4]);
            acc[5] = fmaf(w, bf_hi(p0.z), acc[5]);
            acc[6] = fmaf(w, bf_lo(p0.w), acc[6]);
            acc[7] = fmaf(w, bf_hi(p0.w), acc[7]);
            wsum += w;
            p0 = p1; e0 = e1; p1 = p2; e1 = e2;
        }
    }

    // reduce the 4 edge slots
#pragma unroll
    for (int j = 0; j < 8; ++j) {
        acc[j] += __shfl_xor(acc[j], 16);
        acc[j] += __shfl_xor(acc[j], 32);
    }
    wsum += __shfl_xor(wsum, 16);
    wsum += __shfl_xor(wsum, 32);

    float inv = wsum > 0.f ? 1.f / wsum : 0.f;
    float bl[8];
    *(float4*)&bl[0] = *(const float4*)(b + c0);
    *(float4*)&bl[4] = *(const float4*)(b + c0 + 4);
    float v[8];
#pragma unroll
    for (int j = 0; j < 8; ++j) v[j] = acc[j] * inv + bl[j];

    if (!LOGSOFTMAX) {
        if (lane < 16) {
            unsigned int pk[4];
#pragma unroll
            for (int j = 0; j < 4; ++j) {
                float r0 = v[2 * j]     > 0.f ? v[2 * j]     : 0.f;
                float r1 = v[2 * j + 1] > 0.f ? v[2 * j + 1] : 0.f;
                pk[j] = (unsigned int)f2bf(r0) | ((unsigned int)f2bf(r1) << 16);
            }
            *(uint4*)((unsigned short*)out + (size_t)n * 128 + c0) =
                make_uint4(pk[0], pk[1], pk[2], pk[3]);
        }
    } else {
        float m = v[0];
#pragma unroll
        for (int j = 1; j < 8; ++j) m = fmaxf(m, v[j]);
#pragma unroll
        for (int s = 1; s < 16; s <<= 1) m = fmaxf(m, __shfl_xor(m, s));
        float se = 0.f;
#pragma unroll
        for (int j = 0; j < 8; ++j) se += __expf(v[j] - m);
#pragma unroll
        for (int s = 1; s < 16; s <<= 1) se += __shfl_xor(se, s);
        float ls = m + logf(se);
        if (lane < 16) {
            float* o = (float*)out + (size_t)n * 128 + c0;
            *(float4*)o = make_float4(v[0] - ls, v[1] - ls, v[2] - ls, v[3] - ls);
            *(float4*)(o + 4) = make_float4(v[4] - ls, v[5] - ls, v[6] - ls, v[7] - ls);
        }
    }
}

// ---------------------------------------------------------------------------
extern "C" void kernel_launch(void* const* d_in, const int* in_sizes, int n_in,
                              void* d_out, int out_size, void* d_ws, size_t ws_size,
                              hipStream_t stream) {
    const int*   edge = (const int*)d_in[0];     // (2, E)
    const int*   src  = edge;
    const int*   dst  = edge + N_EDGES;
    const float* feat = (const float*)d_in[1];   // (N, 128)
    const float* W1   = (const float*)d_in[2];
    const float* a1s  = (const float*)d_in[3];
    const float* a1d  = (const float*)d_in[4];
    const float* b1   = (const float*)d_in[5];
    const float* W2   = (const float*)d_in[6];
    const float* a2s  = (const float*)d_in[7];
    const float* a2d  = (const float*)d_in[8];
    const float* b2   = (const float*)d_in[9];
    float* out = (float*)d_out;

    // Workspace: hb | x1b (bf16 N*128) | Wp1 | Wp2 (18432 bf16) | WA (1024 f32)
    //          | esd (N*8 f32) | deg+fillc (2N int) | rowptr | partials | csr_src
    unsigned short* hb  = (unsigned short*)d_ws;
    unsigned short* x1b = hb + (size_t)N_NODES * 128;
    unsigned short* Wp1 = x1b + (size_t)N_NODES * 128;
    unsigned short* Wp2 = Wp1 + 18432;
    float* WA  = (float*)(Wp2 + 18432);
    float* esd = WA + 1024;
    int* deg      = (int*)(esd + (size_t)N_NODES * 8);
    int* fillc    = deg + N_NODES;
    int* rowptr   = fillc + N_NODES;
    int* partials = rowptr + N_NODES;
    int* csr_src  = partials + 512;

    const int node_blk  = (N_NODES + 255) / 256;          // 391
    const int edge_blk  = (N_EDGES + 255) / 256;          // 6250
    const int gemm_blk  = (N_NODES + 127) / 128;          // 782
    const int agg_blk   = (N_NODES + 3) / 4;              // 25000

    // ---- CSR build (shared by both layers) ----
    zero_ints_kernel<<<(2 * N_NODES + 255) / 256, 256, 0, stream>>>(deg, 2 * N_NODES);
    csr_histogram_kernel<<<edge_blk, 256, 0, stream>>>(dst, deg);
    scan1_kernel<<<node_blk, 256, 0, stream>>>(deg, rowptr, partials);
    scan2_kernel<<<1, 512, 0, stream>>>(partials, node_blk);
    scan3_kernel<<<node_blk, 256, 0, stream>>>(rowptr, partials);
    csr_fill_kernel<<<edge_blk, 256, 0, stream>>>(src, dst, rowptr, fillc, csr_src);

    // ---- weight packing (scores folded in as a 9th column tile) ----
    wa_kernel<<<4, 256, 0, stream>>>(W1, a1s, a1d, WA);
    pack_w_kernel<<<72, 256, 0, stream>>>(W1, WA, Wp1);

    // ---- Layer 1 ----
    gemm_mfma_kernel<true><<<gemm_blk, 256, 0, stream>>>(feat, Wp1, hb, esd, N_NODES);
    aggregate_kernel<false><<<agg_blk, 256, 0, stream>>>(
        csr_src, rowptr, deg, esd, hb, b1, x1b);

    // ---- Layer 2 (WA buffer reused; stream-ordered) ----
    wa_kernel<<<4, 256, 0, stream>>>(W2, a2s, a2d, WA);
    pack_w_kernel<<<72, 256, 0, stream>>>(W2, WA, Wp2);
    gemm_mfma_kernel<false><<<gemm_blk, 256, 0, stream>>>(x1b, Wp2, hb, esd, N_NODES);
    aggregate_kernel<true><<<agg_blk, 256, 0, stream>>>(
        csr_src, rowptr, deg, esd, hb, b2, out);
}

// Round 6
// 401.904 us; speedup vs baseline: 5.5229x; 1.1527x over previous
//
#include <hip/hip_runtime.h>
#include <hip/hip_bf16.h>
#include <math.h>

#define N_NODES 100000
#define N_EDGES 1600000
#define NHEADS 4
#define NEG_SLOPE 0.2f
#define NB 1563          // buckets of 64 dst nodes: ceil(100000/64)
#define BCAP 2048        // slab capacity per bucket (avg fill 1024, max ~1200)
// D = H * D_hid = 128 channels for both layers

typedef __attribute__((ext_vector_type(8))) short short8;
typedef __attribute__((ext_vector_type(4))) float f32x4;

// float -> bf16 (round-to-nearest-even), values are finite here
__device__ __forceinline__ unsigned short f2bf(float f) {
    unsigned int u = __float_as_uint(f);
    u += 0x7fffu + ((u >> 16) & 1u);
    return (unsigned short)(u >> 16);
}
__device__ __forceinline__ float bf_lo(unsigned int u) {
    return __uint_as_float(u << 16);
}
__device__ __forceinline__ float bf_hi(unsigned int u) {
    return __uint_as_float(u & 0xffff0000u);
}
__device__ __forceinline__ short8 pack8(float4 f0, float4 f1) {
    short8 v;
    v[0] = (short)f2bf(f0.x); v[1] = (short)f2bf(f0.y);
    v[2] = (short)f2bf(f0.z); v[3] = (short)f2bf(f0.w);
    v[4] = (short)f2bf(f1.x); v[5] = (short)f2bf(f1.y);
    v[6] = (short)f2bf(f1.z); v[7] = (short)f2bf(f1.w);
    return v;
}

// ---------------------------------------------------------------------------
// Pack [W (128x128) | WA (128x8) pad to 16] into per-lane MFMA B-fragment
// order (bf16), 9 column-tiles. WA[k][c] = <W[k][hd*32..], a[hd]> is computed
// inline for the 9th tile (es/ed are linear in h, so scores fold into GEMM).
// Wp[((ct*4+kc)*64+lane)*8+j] = srcmat[k=kc*32+(lane>>4)*8+j][n=ct*16+(lane&15)]
// ---------------------------------------------------------------------------
__global__ void pack_w_kernel(const float* __restrict__ W,
                              const float* __restrict__ a_src,
                              const float* __restrict__ a_dst,
                              unsigned short* __restrict__ Wp) {
    int idx = blockIdx.x * 256 + threadIdx.x;   // 0..18431
    if (idx >= 18432) return;
    int j    = idx & 7;
    int lane = (idx >> 3) & 63;
    int kc   = (idx >> 9) & 3;
    int ct   = idx >> 11;                        // 0..8
    int k = kc * 32 + ((lane >> 4) & 3) * 8 + j;
    int n = lane & 15;
    float v = 0.f;
    if (ct < 8) {
        v = W[k * 128 + ct * 16 + n];
    } else if (n < 8) {
        int hd = n & 3;
        const float* av = (n < 4 ? a_src : a_dst) + hd * 32;
        const float* wr = W + k * 128 + hd * 32;
#pragma unroll
        for (int t = 0; t < 32; ++t) v = fmaf(wr[t], av[t], v);
    }
    Wp[idx] = f2bf(v);
}

// ---------------------------------------------------------------------------
// MFMA GEMM + fused scores: [h | esd] = x @ [W | WA].
// Block 256 thr = 4 waves; 128 rows/block (2 row-tiles of 16 per wave).
// K=128 as 4 chunks, 9 col-tiles of mfma_f32_16x16x32_bf16, fp32 accumulate.
// XF32: layer-1 reads fp32 features and converts inline (no convert pass).
// D layout: col=lane&15, row=quad*4+i.
// ---------------------------------------------------------------------------
template <bool XF32>
__global__ __launch_bounds__(256) void gemm_mfma_kernel(
        const void* __restrict__ xv,
        const unsigned short* __restrict__ Wp,
        unsigned short* __restrict__ h, float* __restrict__ esd, int n_rows) {
    __shared__ unsigned short Wl[18432];   // 36 KB

    const int t = threadIdx.x;
    {
        const uint4* s4 = (const uint4*)Wp;
        uint4* d4 = (uint4*)Wl;
#pragma unroll
        for (int p = 0; p < 9; ++p) d4[p * 256 + t] = s4[p * 256 + t];
    }
    __syncthreads();

    const int lane = t & 63, wave = t >> 6;
    const int l15 = lane & 15, quad = lane >> 4;
    const int rbase = blockIdx.x * 128 + wave * 32;

    short8 a[2][4];
#pragma unroll
    for (int rt = 0; rt < 2; ++rt) {
        int r = rbase + rt * 16 + l15;
        r = r < n_rows ? r : n_rows - 1;         // clamp; stores are guarded
        if (XF32) {
            const float* xr = (const float*)xv + (size_t)r * 128 + quad * 8;
#pragma unroll
            for (int kc = 0; kc < 4; ++kc) {
                float4 f0 = *(const float4*)(xr + kc * 32);
                float4 f1 = *(const float4*)(xr + kc * 32 + 4);
                a[rt][kc] = pack8(f0, f1);
            }
        } else {
            const unsigned short* xr =
                (const unsigned short*)xv + (size_t)r * 128 + quad * 8;
#pragma unroll
            for (int kc = 0; kc < 4; ++kc)
                a[rt][kc] = *(const short8*)(xr + kc * 32);
        }
    }

    f32x4 acc[2][9];
#pragma unroll
    for (int rt = 0; rt < 2; ++rt)
#pragma unroll
        for (int ct = 0; ct < 9; ++ct)
            acc[rt][ct] = (f32x4){0.f, 0.f, 0.f, 0.f};

#pragma unroll
    for (int ct = 0; ct < 9; ++ct) {
#pragma unroll
        for (int kc = 0; kc < 4; ++kc) {
            short8 b = *(const short8*)&Wl[((ct * 4 + kc) * 64 + lane) * 8];
            acc[0][ct] = __builtin_amdgcn_mfma_f32_16x16x32_bf16(
                a[0][kc], b, acc[0][ct], 0, 0, 0);
            acc[1][ct] = __builtin_amdgcn_mfma_f32_16x16x32_bf16(
                a[1][kc], b, acc[1][ct], 0, 0, 0);
        }
    }

#pragma unroll
    for (int rt = 0; rt < 2; ++rt) {
#pragma unroll
        for (int i = 0; i < 4; ++i) {
            int r = rbase + rt * 16 + quad * 4 + i;
            if (r < n_rows) {
                unsigned short* hp = h + (size_t)r * 128 + l15;
#pragma unroll
                for (int ct = 0; ct < 8; ++ct)
                    hp[ct * 16] = f2bf(acc[rt][ct][i]);
                if (l15 < 8) esd[r * 8 + l15] = acc[rt][8][i];
            }
        }
    }
}

// ---------------------------------------------------------------------------
// CSR build, two-level bucket scheme (graph shared by both layers).
// Level 1: edges -> NB slabs by dst>>6 (sequential stream per slab ->
// L2 write-combining, ~1x amplification vs 16x for random 4B scatter).
// Record = src | (dst&63)<<17 (src < 2^17). Level 2: per-bucket LDS
// histogram/fill; csr_src writes land in the bucket's contiguous range.
// ---------------------------------------------------------------------------
__global__ void zero_ints_kernel(int* __restrict__ p, int n) {
    int i = blockIdx.x * 256 + threadIdx.x;
    if (i < n) p[i] = 0;
}

__global__ void bucket_fill_kernel(const int* __restrict__ src,
                                   const int* __restrict__ dst,
                                   int* __restrict__ bcnt,
                                   unsigned int* __restrict__ slab) {
    int e = blockIdx.x * 256 + threadIdx.x;
    if (e >= N_EDGES) return;
    int d = dst[e];
    int b = d >> 6;
    int pos = atomicAdd(&bcnt[b * 16], 1);      // 64B-padded counters
    slab[(size_t)b * BCAP + pos] = (unsigned int)src[e] | ((unsigned int)(d & 63) << 17);
}

__global__ __launch_bounds__(256) void bucket_hist_kernel(
        const int* __restrict__ bcnt, const unsigned int* __restrict__ slab,
        int* __restrict__ deg) {
    __shared__ int hist[64];
    const int b = blockIdx.x;
    if (threadIdx.x < 64) hist[threadIdx.x] = 0;
    __syncthreads();
    const int m = bcnt[b * 16];
    const unsigned int* sp = slab + (size_t)b * BCAP;
    for (int i = threadIdx.x; i < m; i += 256)
        atomicAdd(&hist[sp[i] >> 17], 1);
    __syncthreads();
    if (threadIdx.x < 64) {
        int node = b * 64 + threadIdx.x;
        if (node < N_NODES) deg[node] = hist[threadIdx.x];
    }
}

__global__ __launch_bounds__(256) void scan1_kernel(const int* __restrict__ deg,
                                                    int* __restrict__ rowptr,
                                                    int* __restrict__ partials) {
    __shared__ int wsum[4];
    int i = blockIdx.x * 256 + threadIdx.x;
    int lane = threadIdx.x & 63, wave = threadIdx.x >> 6;
    int orig = (i < N_NODES) ? deg[i] : 0;
    int v = orig;
#pragma unroll
    for (int off = 1; off < 64; off <<= 1) {
        int t = __shfl_up(v, off);
        if (lane >= off) v += t;
    }
    if (lane == 63) wsum[wave] = v;
    __syncthreads();
    int woff = 0;
#pragma unroll
    for (int w = 0; w < 4; ++w) if (w < wave) woff += wsum[w];
    if (i < N_NODES) rowptr[i] = v - orig + woff;
    if (threadIdx.x == 0)
        partials[blockIdx.x] = wsum[0] + wsum[1] + wsum[2] + wsum[3];
}

__global__ __launch_bounds__(512) void scan2_kernel(int* __restrict__ partials,
                                                    int nb) {
    __shared__ int wsum[8];
    int i = threadIdx.x;
    int lane = i & 63, wave = i >> 6;
    int orig = (i < nb) ? partials[i] : 0;
    int v = orig;
#pragma unroll
    for (int off = 1; off < 64; off <<= 1) {
        int t = __shfl_up(v, off);
        if (lane >= off) v += t;
    }
    if (lane == 63) wsum[wave] = v;
    __syncthreads();
    int woff = 0;
#pragma unroll
    for (int w = 0; w < 8; ++w) if (w < wave) woff += wsum[w];
    if (i < nb) partials[i] = v - orig + woff;
}

__global__ void scan3_kernel(int* __restrict__ rowptr,
                             const int* __restrict__ partials) {
    int i = blockIdx.x * 256 + threadIdx.x;
    if (i < N_NODES) rowptr[i] += partials[blockIdx.x];
}

__global__ __launch_bounds__(256) void bucket_scatter_kernel(
        const int* __restrict__ bcnt, const unsigned int* __restrict__ slab,
        const int* __restrict__ rowptr, int* __restrict__ csr_src) {
    __shared__ int rp[64];
    __shared__ int cnt[64];
    const int b = blockIdx.x;
    if (threadIdx.x < 64) {
        int node = b * 64 + threadIdx.x;
        rp[threadIdx.x] = node < N_NODES ? rowptr[node] : 0;
        cnt[threadIdx.x] = 0;
    }
    __syncthreads();
    const int m = bcnt[b * 16];
    const unsigned int* sp = slab + (size_t)b * BCAP;
    for (int i = threadIdx.x; i < m; i += 256) {
        unsigned int rec = sp[i];
        int local = rec >> 17;
        int pos = rp[local] + atomicAdd(&cnt[local], 1);
        csr_src[pos] = (int)(rec & 0x1FFFFu);
    }
}

// ---------------------------------------------------------------------------
// Gather aggregation, one wave per dst node.
// Lane = (edge-slot eo in [0,4)) x (channel-group cl in [0,16), 8 ch each).
// 4 edges (4 full 256B rows) gathered per wave-iteration; trip ~deg/4.
// All edge indices loaded once (coalesced 64-wide) and shfl-distributed;
// payload+score prefetched 2 iterations ahead -> ~12 edges in flight.
// Cross-eo reduction: 2x shfl_xor per accumulator.
// Epilogue fused: RELU->bf16 (layer 1) or log_softmax->fp32 (layer 2).
// Softmax max-shift dropped: shift-invariant, logits are O(1) in fp32.
// ---------------------------------------------------------------------------
template <bool LOGSOFTMAX>
__global__ __launch_bounds__(256) void aggregate_kernel(
        const int* __restrict__ csr_src, const int* __restrict__ rowptr,
        const int* __restrict__ deg, const float* __restrict__ esd,
        const unsigned short* __restrict__ hb, const float* __restrict__ b,
        void* __restrict__ out) {
    const int lane = threadIdx.x & 63;
    const int wave = threadIdx.x >> 6;
    const int n = blockIdx.x * 4 + wave;
    if (n >= N_NODES) return;
    const int eo = lane >> 4;          // edge slot
    const int cl = lane & 15;          // channel group: channels cl*8..cl*8+7
    const int c0 = cl * 8;
    const int hd = cl >> 2;
    const float edn = esd[n * 8 + 4 + hd];
    const int base = rowptr[n];
    const int dg = deg[n];

    float acc[8] = {0.f, 0.f, 0.f, 0.f, 0.f, 0.f, 0.f, 0.f};
    float wsum = 0.f;

    if (dg > 0) {
        const int myidx = csr_src[base + (lane < dg ? lane : dg - 1)];
        const int nit = (dg + 3) >> 2;

        auto getS = [&](int j) -> int {
            int o = 4 * j + eo;
            if (4 * j < 64) return __shfl(myidx, o);   // j wave-uniform
            int oc = o < dg ? o : dg - 1;
            return csr_src[base + oc];
        };
        auto loadP = [&](int s) -> uint4 {
            return *(const uint4*)(hb + (size_t)s * 128 + c0);
        };

        int s0 = getS(0);
        uint4 p0 = loadP(s0);
        float e0 = esd[s0 * 8 + hd];
        uint4 p1 = p0; float e1 = e0;
        if (nit > 1) {
            int s1 = getS(1);
            p1 = loadP(s1);
            e1 = esd[s1 * 8 + hd];
        }
        for (int j = 0; j < nit; ++j) {
            uint4 p2 = p1; float e2 = e1;
            if (j + 2 < nit) {
                int s2 = getS(j + 2);
                p2 = loadP(s2);
                e2 = esd[s2 * 8 + hd];
            }
            int o = 4 * j + eo;
            float sc = e0 + edn;
            sc = sc > 0.f ? sc : NEG_SLOPE * sc;
            float w = (o < dg) ? __expf(sc) : 0.f;
            acc[0] = fmaf(w, bf_lo(p0.x), acc[0]);
            acc[1] = fmaf(w, bf_hi(p0.x), acc[1]);
            acc[2] = fmaf(w, bf_lo(p0.y), acc[2]);
            acc[3] = fmaf(w, bf_hi(p0.y), acc[3]);
            acc[4] = fmaf(w, bf_lo(p0.z), acc[4]);
            acc[5] = fmaf(w, bf_hi(p0.z), acc[5]);
            acc[6] = fmaf(w, bf_lo(p0.w), acc[6]);
            acc[7] = fmaf(w, bf_hi(p0.w), acc[7]);
            wsum += w;
            p0 = p1; e0 = e1; p1 = p2; e1 = e2;
        }
    }

    // reduce the 4 edge slots
#pragma unroll
    for (int j = 0; j < 8; ++j) {
        acc[j] += __shfl_xor(acc[j], 16);
        acc[j] += __shfl_xor(acc[j], 32);
    }
    wsum += __shfl_xor(wsum, 16);
    wsum += __shfl_xor(wsum, 32);

    float inv = wsum > 0.f ? 1.f / wsum : 0.f;
    float bl[8];
    *(float4*)&bl[0] = *(const float4*)(b + c0);
    *(float4*)&bl[4] = *(const float4*)(b + c0 + 4);
    float v[8];
#pragma unroll
    for (int j = 0; j < 8; ++j) v[j] = acc[j] * inv + bl[j];

    if (!LOGSOFTMAX) {
        if (lane < 16) {
            unsigned int pk[4];
#pragma unroll
            for (int j = 0; j < 4; ++j) {
                float r0 = v[2 * j]     > 0.f ? v[2 * j]     : 0.f;
                float r1 = v[2 * j + 1] > 0.f ? v[2 * j + 1] : 0.f;
                pk[j] = (unsigned int)f2bf(r0) | ((unsigned int)f2bf(r1) << 16);
            }
            *(uint4*)((unsigned short*)out + (size_t)n * 128 + c0) =
                make_uint4(pk[0], pk[1], pk[2], pk[3]);
        }
    } else {
        float m = v[0];
#pragma unroll
        for (int j = 1; j < 8; ++j) m = fmaxf(m, v[j]);
#pragma unroll
        for (int s = 1; s < 16; s <<= 1) m = fmaxf(m, __shfl_xor(m, s));
        float se = 0.f;
#pragma unroll
        for (int j = 0; j < 8; ++j) se += __expf(v[j] - m);
#pragma unroll
        for (int s = 1; s < 16; s <<= 1) se += __shfl_xor(se, s);
        float ls = m + logf(se);
        if (lane < 16) {
            float* o = (float*)out + (size_t)n * 128 + c0;
            *(float4*)o = make_float4(v[0] - ls, v[1] - ls, v[2] - ls, v[3] - ls);
            *(float4*)(o + 4) = make_float4(v[4] - ls, v[5] - ls, v[6] - ls, v[7] - ls);
        }
    }
}

// ---------------------------------------------------------------------------
extern "C" void kernel_launch(void* const* d_in, const int* in_sizes, int n_in,
                              void* d_out, int out_size, void* d_ws, size_t ws_size,
                              hipStream_t stream) {
    const int*   edge = (const int*)d_in[0];     // (2, E)
    const int*   src  = edge;
    const int*   dst  = edge + N_EDGES;
    const float* feat = (const float*)d_in[1];   // (N, 128)
    const float* W1   = (const float*)d_in[2];
    const float* a1s  = (const float*)d_in[3];
    const float* a1d  = (const float*)d_in[4];
    const float* b1   = (const float*)d_in[5];
    const float* W2   = (const float*)d_in[6];
    const float* a2s  = (const float*)d_in[7];
    const float* a2d  = (const float*)d_in[8];
    const float* b2   = (const float*)d_in[9];
    float* out = (float*)d_out;

    // Workspace: hb | x1b (bf16 N*128) | Wp1 | Wp2 (18432 bf16) | esd (N*8 f32)
    //          | deg | rowptr (N int) | partials (512) | bcnt (NB*16 int)
    //          | slab (NB*BCAP uint) | csr_src (E int)
    unsigned short* hb  = (unsigned short*)d_ws;
    unsigned short* x1b = hb + (size_t)N_NODES * 128;
    unsigned short* Wp1 = x1b + (size_t)N_NODES * 128;
    unsigned short* Wp2 = Wp1 + 18432;
    float* esd = (float*)(Wp2 + 18432);
    int* deg      = (int*)(esd + (size_t)N_NODES * 8);
    int* rowptr   = deg + N_NODES;
    int* partials = rowptr + N_NODES;
    int* bcnt     = partials + 512;
    unsigned int* slab = (unsigned int*)(bcnt + NB * 16);
    int* csr_src  = (int*)(slab + (size_t)NB * BCAP);

    const int node_blk  = (N_NODES + 255) / 256;          // 391
    const int edge_blk  = (N_EDGES + 255) / 256;          // 6250
    const int gemm_blk  = (N_NODES + 127) / 128;          // 782
    const int agg_blk   = (N_NODES + 3) / 4;              // 25000

    // ---- CSR build (shared by both layers) ----
    zero_ints_kernel<<<(NB * 16 + 255) / 256, 256, 0, stream>>>(bcnt, NB * 16);
    bucket_fill_kernel<<<edge_blk, 256, 0, stream>>>(src, dst, bcnt, slab);
    bucket_hist_kernel<<<NB, 256, 0, stream>>>(bcnt, slab, deg);
    scan1_kernel<<<node_blk, 256, 0, stream>>>(deg, rowptr, partials);
    scan2_kernel<<<1, 512, 0, stream>>>(partials, node_blk);
    scan3_kernel<<<node_blk, 256, 0, stream>>>(rowptr, partials);
    bucket_scatter_kernel<<<NB, 256, 0, stream>>>(bcnt, slab, rowptr, csr_src);

    // ---- weight packing (scores folded in as a 9th column tile) ----
    pack_w_kernel<<<72, 256, 0, stream>>>(W1, a1s, a1d, Wp1);
    pack_w_kernel<<<72, 256, 0, stream>>>(W2, a2s, a2d, Wp2);

    // ---- Layer 1 ----
    gemm_mfma_kernel<true><<<gemm_blk, 256, 0, stream>>>(feat, Wp1, hb, esd, N_NODES);
    aggregate_kernel<false><<<agg_blk, 256, 0, stream>>>(
        csr_src, rowptr, deg, esd, hb, b1, x1b);

    // ---- Layer 2 ----
    gemm_mfma_kernel<false><<<gemm_blk, 256, 0, stream>>>(x1b, Wp2, hb, esd, N_NODES);
    aggregate_kernel<true><<<agg_blk, 256, 0, stream>>>(
        csr_src, rowptr, deg, esd, hb, b2, out);
}